// Round 1
// 101.975 us; speedup vs baseline: 1.0919x; 1.0919x over previous
//
#include <hip/hip_runtime.h>

// Problem constants (from reference): B=4, C=5, H=64, W=64, N=4096
#define Bq  4
#define Cc  5
#define Hh  64
#define Ww  64
#define HW  (Hh * Ww)       // 4096
#define CHW (Cc * HW)       // 20480
#define HW4 (HW / 4)        // 1024 float4 per plane

// ---------------------------------------------------------------------------
// Kernel A: K/V map precompute, float4 over spatial dim, with fused y = x copy.
// One thread per (b, p4) group of 4 spatial positions.
// ---------------------------------------------------------------------------
__global__ __launch_bounds__(256) void kv_precompute_f4(
    const float4* __restrict__ x4,
    const float* __restrict__ kw, const float* __restrict__ kb,
    const float* __restrict__ vw, const float* __restrict__ vb,
    float4* __restrict__ K4, float4* __restrict__ V4,
    float4* __restrict__ y4)
{
    int t = blockIdx.x * blockDim.x + threadIdx.x;
    if (t >= Bq * HW4) return;
    int b = t >> 10;            // / HW4
    int p = t & (HW4 - 1);      // % HW4
    const int base = b * (Cc * HW4);

    float4 xi[Cc];
#pragma unroll
    for (int c = 0; c < Cc; ++c) {
        xi[c] = x4[base + c * HW4 + p];
        y4[base + c * HW4 + p] = xi[c];     // fused y = x copy
    }
#pragma unroll
    for (int o = 0; o < Cc; ++o) {
        float kbo = kb[o], vbo = vb[o];
        float4 ka = {kbo, kbo, kbo, kbo};
        float4 va = {vbo, vbo, vbo, vbo};
#pragma unroll
        for (int c = 0; c < Cc; ++c) {
            float kwv = kw[o * Cc + c];
            float vwv = vw[o * Cc + c];
            ka.x += kwv * xi[c].x; ka.y += kwv * xi[c].y;
            ka.z += kwv * xi[c].z; ka.w += kwv * xi[c].w;
            va.x += vwv * xi[c].x; va.y += vwv * xi[c].y;
            va.z += vwv * xi[c].z; va.w += vwv * xi[c].w;
        }
        K4[base + o * HW4 + p] = ka;
        V4[base + o * HW4 + p] = va;
    }
}

// ---------------------------------------------------------------------------
// Kernel B: one 64-lane wave per query n; each lane handles 4 positions per
// iteration via float4 (coalesced dwordx4 loads, 16 iterations total).
// Online softmax, butterfly shuffle-merge, scatter gamma*out + xi into y.
// ---------------------------------------------------------------------------
__global__ __launch_bounds__(256) void attn_scatter_f4(
    const float* __restrict__ x,
    const float* __restrict__ qw, const float* __restrict__ qb,
    const float4* __restrict__ K4, const float4* __restrict__ V4,
    const float* __restrict__ gamma,
    const int* __restrict__ idx_b, const int* __restrict__ idx_h,
    const int* __restrict__ idx_w,
    float* __restrict__ y, int N)
{
    int gtid = blockIdx.x * blockDim.x + threadIdx.x;
    int n    = gtid >> 6;     // wave id
    int lane = threadIdx.x & 63;
    if (n >= N) return;

    const int b   = idx_b[n];
    const int pos = idx_h[n] * Ww + idx_w[n];

    // q[o] = sum_c qw[o,c]*x[b,c,pos] + qb[o]   (wave-uniform; broadcast loads)
    float xq[Cc];
#pragma unroll
    for (int c = 0; c < Cc; ++c) xq[c] = x[b * CHW + c * HW + pos];
    float q[Cc];
#pragma unroll
    for (int o = 0; o < Cc; ++o) {
        float a = qb[o];
#pragma unroll
        for (int c = 0; c < Cc; ++c) a += qw[o * Cc + c] * xq[c];
        q[o] = a;
    }

    const float4* Kb = K4 + b * (Cc * HW4);
    const float4* Vb = V4 + b * (Cc * HW4);

    float m = -1e30f, l = 0.f;
    float acc[Cc] = {0.f, 0.f, 0.f, 0.f, 0.f};

    for (int p = lane; p < HW4; p += 64) {   // 16 iterations
        float4 kc[Cc], vc[Cc];
#pragma unroll
        for (int c = 0; c < Cc; ++c) {
            kc[c] = Kb[c * HW4 + p];
            vc[c] = Vb[c * HW4 + p];
        }
        float ex = q[0]*kc[0].x + q[1]*kc[1].x + q[2]*kc[2].x + q[3]*kc[3].x + q[4]*kc[4].x;
        float ey = q[0]*kc[0].y + q[1]*kc[1].y + q[2]*kc[2].y + q[3]*kc[3].y + q[4]*kc[4].y;
        float ez = q[0]*kc[0].z + q[1]*kc[1].z + q[2]*kc[2].z + q[3]*kc[3].z + q[4]*kc[4].z;
        float ew = q[0]*kc[0].w + q[1]*kc[1].w + q[2]*kc[2].w + q[3]*kc[3].w + q[4]*kc[4].w;

        float m4 = fmaxf(fmaxf(ex, ey), fmaxf(ez, ew));
        float nm = fmaxf(m, m4);
        float a  = __expf(m - nm);               // 0 on first iter, else rescale
        float w0 = __expf(ex - nm);
        float w1 = __expf(ey - nm);
        float w2 = __expf(ez - nm);
        float w3 = __expf(ew - nm);
        l = l * a + ((w0 + w1) + (w2 + w3));
#pragma unroll
        for (int c = 0; c < Cc; ++c)
            acc[c] = acc[c] * a +
                     ((w0 * vc[c].x + w1 * vc[c].y) + (w2 * vc[c].z + w3 * vc[c].w));
        m = nm;
    }

    // Butterfly merge of (m, l, acc[5]) across the 64-lane wave.
#pragma unroll
    for (int off = 32; off >= 1; off >>= 1) {
        float m2 = __shfl_xor(m, off, 64);
        float l2 = __shfl_xor(l, off, 64);
        float nm = fmaxf(m, m2);
        float a  = __expf(m - nm);
        float a2 = __expf(m2 - nm);
        l = l * a + l2 * a2;
#pragma unroll
        for (int c = 0; c < Cc; ++c) {
            float o2 = __shfl_xor(acc[c], off, 64);
            acc[c] = acc[c] * a + o2 * a2;
        }
        m = nm;
    }

    if (lane < Cc) {
        int c = lane;
        float xi = x[b * CHW + c * HW + pos];
        y[b * CHW + c * HW + pos] = gamma[0] * (acc[c] / l) + xi;
    }
}

// ---------------------------------------------------------------------------
// Fallback (no workspace): original scalar inline-KV path.
// ---------------------------------------------------------------------------
__global__ void attn_scatter_inline(
    const float* __restrict__ x,
    const float* __restrict__ qw, const float* __restrict__ qb,
    const float* __restrict__ kw, const float* __restrict__ kb,
    const float* __restrict__ vw, const float* __restrict__ vb,
    const float* __restrict__ gamma,
    const int* __restrict__ idx_b, const int* __restrict__ idx_h,
    const int* __restrict__ idx_w,
    float* __restrict__ y, int N)
{
    int gtid = blockIdx.x * blockDim.x + threadIdx.x;
    int n    = gtid >> 6;
    int lane = threadIdx.x & 63;
    if (n >= N) return;

    const int b   = idx_b[n];
    const int pos = idx_h[n] * Ww + idx_w[n];

    float xq[Cc];
#pragma unroll
    for (int c = 0; c < Cc; ++c) xq[c] = x[b * CHW + c * HW + pos];
    float q[Cc];
#pragma unroll
    for (int o = 0; o < Cc; ++o) {
        float a = qb[o];
#pragma unroll
        for (int c = 0; c < Cc; ++c) a += qw[o * Cc + c] * xq[c];
        q[o] = a;
    }

    const float* Xb = x + b * CHW;
    float m = -1e30f, l = 0.f;
    float acc[Cc] = {0.f, 0.f, 0.f, 0.f, 0.f};

    for (int p = lane; p < HW; p += 64) {
        float xi[Cc];
#pragma unroll
        for (int c = 0; c < Cc; ++c) xi[c] = Xb[c * HW + p];
        float kv_k[Cc], kv_v[Cc];
#pragma unroll
        for (int o = 0; o < Cc; ++o) {
            float ka = kb[o], va = vb[o];
#pragma unroll
            for (int c = 0; c < Cc; ++c) {
                ka += kw[o * Cc + c] * xi[c];
                va += vw[o * Cc + c] * xi[c];
            }
            kv_k[o] = ka;
            kv_v[o] = va;
        }
        float e = q[0]*kv_k[0] + q[1]*kv_k[1] + q[2]*kv_k[2] + q[3]*kv_k[3] + q[4]*kv_k[4];
        float nm  = fmaxf(m, e);
        float a   = __expf(m - nm);
        float wgt = __expf(e - nm);
        l = l * a + wgt;
#pragma unroll
        for (int c = 0; c < Cc; ++c) acc[c] = acc[c] * a + wgt * kv_v[c];
        m = nm;
    }

#pragma unroll
    for (int off = 32; off >= 1; off >>= 1) {
        float m2 = __shfl_xor(m, off, 64);
        float l2 = __shfl_xor(l, off, 64);
        float nm = fmaxf(m, m2);
        float a  = __expf(m - nm);
        float a2 = __expf(m2 - nm);
        l = l * a + l2 * a2;
#pragma unroll
        for (int c = 0; c < Cc; ++c) {
            float o2 = __shfl_xor(acc[c], off, 64);
            acc[c] = acc[c] * a + o2 * a2;
        }
        m = nm;
    }

    if (lane < Cc) {
        int c = lane;
        float xi = x[b * CHW + c * HW + pos];
        y[b * CHW + c * HW + pos] = gamma[0] * (acc[c] / l) + xi;
    }
}

// ---------------------------------------------------------------------------
extern "C" void kernel_launch(void* const* d_in, const int* in_sizes, int n_in,
                              void* d_out, int out_size, void* d_ws, size_t ws_size,
                              hipStream_t stream) {
    const float* x     = (const float*)d_in[0];
    // d_in[1] = x_teature: unused by the reference
    const float* qw    = (const float*)d_in[2];
    const float* qb    = (const float*)d_in[3];
    const float* kw    = (const float*)d_in[4];
    const float* kb    = (const float*)d_in[5];
    const float* vw    = (const float*)d_in[6];
    const float* vb    = (const float*)d_in[7];
    const float* gamma = (const float*)d_in[8];
    const int*   idx_b = (const int*)d_in[9];
    const int*   idx_h = (const int*)d_in[10];
    const int*   idx_w = (const int*)d_in[11];
    const int    N     = in_sizes[9];   // idx_b element count (= index_len)

    float* y = (float*)d_out;

    const size_t kv_bytes = (size_t)2 * Bq * CHW * sizeof(float); // 640 KB
    const int wavesPerBlock = 4;                   // 256 threads
    const int grid_b = (N + wavesPerBlock - 1) / wavesPerBlock;

    if (ws_size >= kv_bytes) {
        float* K = (float*)d_ws;
        float* V = K + (size_t)Bq * CHW;
        // y=x copy is fused into kv_precompute_f4 (it already reads all of x).
        kv_precompute_f4<<<(Bq * HW4 + 255) / 256, 256, 0, stream>>>(
            (const float4*)x, kw, kb, vw, vb, (float4*)K, (float4*)V, (float4*)y);
        attn_scatter_f4<<<grid_b, 256, 0, stream>>>(
            x, qw, qb, (const float4*)K, (const float4*)V, gamma,
            idx_b, idx_h, idx_w, y, N);
    } else {
        hipMemcpyAsync(y, x, (size_t)Bq * CHW * sizeof(float),
                       hipMemcpyDeviceToDevice, stream);
        attn_scatter_inline<<<grid_b, 256, 0, stream>>>(
            x, qw, qb, kw, kb, vw, vb, gamma, idx_b, idx_h, idx_w, y, N);
    }
}